// Round 11
// baseline (138.015 us; speedup 1.0000x reference)
//
#include <hip/hip_runtime.h>
#include <math.h>

#define B_SZ   4
#define N_SEQ  197
#define DIMC   2048
#define HEADS  32
#define HD     64
#define WIN    8
#define M_ROWS (B_SZ * N_SEQ)   // 788
#define M_PAD  896               // 7 * 128

using f32x4 = __attribute__((ext_vector_type(4))) float;
using s16x8 = __attribute__((ext_vector_type(8))) short;

__device__ inline ushort f2bf(float f) {
  uint x = __float_as_uint(f);
  uint r = (x + 0x7fffu + ((x >> 16) & 1u)) >> 16;  // RNE
  return (ushort)r;
}
__device__ inline float bf2f(ushort u) {
  return __uint_as_float(((uint)u) << 16);
}

__device__ inline void gload16(const ushort* g, ushort* l) {
  __builtin_amdgcn_global_load_lds(
      (const __attribute__((address_space(1))) unsigned int*)g,
      (__attribute__((address_space(3))) unsigned int*)l, 16, 0, 0);
}

// -- fused: fp32->bf16 cvt (x, qkv_w, proj_w) + zero (qkv_f32, out) ----------
#define NX  (M_ROWS * DIMC / 8)        // 201728
#define NQ  (3 * DIMC * DIMC / 8)      // 1572864
#define NP  (DIMC * DIMC / 8)          // 524288
#define NZQ (M_ROWS * 3 * DIMC / 8)    // 605184  (qkv fp32 zero)
#define NZO (M_ROWS * DIMC / 8)        // 201728  (out zero)

__global__ __launch_bounds__(256)
void cvt_all(const float* __restrict__ x,  const float* __restrict__ qw,
             const float* __restrict__ pw, ushort* __restrict__ xb,
             ushort* __restrict__ qwb, ushort* __restrict__ pwb,
             float* __restrict__ qkvz, float* __restrict__ outz) {
  int i = blockIdx.x * 256 + threadIdx.x;
  const float* src; ushort* dst; int idx;
  if (i < NX)                { src = x;  dst = xb;  idx = i; }
  else if (i < NX + NQ)      { src = qw; dst = qwb; idx = i - NX; }
  else if (i < NX + NQ + NP) { src = pw; dst = pwb; idx = i - NX - NQ; }
  else if (i < NX + NQ + NP + NZQ) {
    int z = i - NX - NQ - NP;
    ((f32x4*)qkvz)[2 * z]     = (f32x4){0.f, 0.f, 0.f, 0.f};
    ((f32x4*)qkvz)[2 * z + 1] = (f32x4){0.f, 0.f, 0.f, 0.f};
    return;
  } else if (i < NX + NQ + NP + NZQ + NZO) {
    int z = i - NX - NQ - NP - NZQ;
    ((f32x4*)outz)[2 * z]     = (f32x4){0.f, 0.f, 0.f, 0.f};
    ((f32x4*)outz)[2 * z + 1] = (f32x4){0.f, 0.f, 0.f, 0.f};
    return;
  } else return;
  f32x4 a = ((const f32x4*)src)[2 * idx];
  f32x4 b = ((const f32x4*)src)[2 * idx + 1];
  ushort4 u0, u1;
  u0.x = f2bf(a.x); u0.y = f2bf(a.y); u0.z = f2bf(a.z); u0.w = f2bf(a.w);
  u1.x = f2bf(b.x); u1.y = f2bf(b.y); u1.z = f2bf(b.z); u1.w = f2bf(b.w);
  ((ushort4*)dst)[2 * idx]     = u0;
  ((ushort4*)dst)[2 * idx + 1] = u1;
}

// ---- GEMM: C(fp32) += A(bf16,MxK) @ Bw(bf16,NxK)^T over K-slice z ----------
// 128x128 tile, 4 waves, 64x64/wave: 16 MFMA + 8 ds_read_b128 per K-step.
// Depth-2 counted-vmcnt pipeline, 3 LDS buffers, 2-way slot swizzle.
// Epilogue: fp32 atomicAdd into zeroed C (split-K=2 -> exactly 2 addends per
// element -> order-invariant, deterministic). bias added by z==0 blocks.
__global__ __launch_bounds__(256, 3)
void gemm_bt_atomic(const ushort* __restrict__ A, const ushort* __restrict__ Bw,
                    float* __restrict__ C, const float* __restrict__ bias,
                    int Mdim, int Ndim, int Kfull, int Ksplit) {
  __shared__ ushort As[3][128 * 32];
  __shared__ ushort Bs[3][128 * 32];
  const int tid  = threadIdx.x;
  const int lane = tid & 63;
  const int wave = tid >> 6;

  const int nwg  = gridDim.x * gridDim.y;
  const int phys = blockIdx.y * gridDim.x + blockIdx.x;
  const int cpx  = nwg >> 3;
  const int lg   = (phys & 7) * cpx + (phys >> 3);
  const int m0 = (lg % gridDim.x) * 128;
  const int n0 = (lg / gridDim.x) * 128;
  const int koff = blockIdx.z * Ksplit;

  const int wr = (wave >> 1) * 64;
  const int wc = (wave & 1) * 64;
  const int fr = lane & 15;
  const int kg = lane >> 4;
  const int srow = lane >> 2;
  const int scol = ((lane & 3) ^ ((srow >> 1) & 3)) * 8;
  const int rdA  = (kg ^ ((fr >> 1) & 3)) * 8;

  f32x4 acc[4][4];
#pragma unroll
  for (int i = 0; i < 4; ++i)
#pragma unroll
    for (int j = 0; j < 4; ++j)
      acc[i][j] = (f32x4){0.f, 0.f, 0.f, 0.f};

  const ushort* Asrc0 = A  + (size_t)(m0 + wave * 32 + srow)      * Kfull + koff + scol;
  const ushort* Asrc1 = A  + (size_t)(m0 + wave * 32 + 16 + srow) * Kfull + koff + scol;
  const ushort* Bsrc0 = Bw + (size_t)(n0 + wave * 32 + srow)      * Kfull + koff + scol;
  const ushort* Bsrc1 = Bw + (size_t)(n0 + wave * 32 + 16 + srow) * Kfull + koff + scol;

  const int nt = Ksplit >> 5;

  auto STAGE = [&](int kk, int b) {
    const int k = kk << 5;
    gload16(Asrc0 + k, &As[b][wave * 1024]);
    gload16(Asrc1 + k, &As[b][wave * 1024 + 512]);
    gload16(Bsrc0 + k, &Bs[b][wave * 1024]);
    gload16(Bsrc1 + k, &Bs[b][wave * 1024 + 512]);
  };

  STAGE(0, 0);
  STAGE(1, 1);

  int cur = 0, s2 = 2;
  for (int t = 0; t < nt; ++t) {
    if (t < nt - 1) asm volatile("s_waitcnt vmcnt(4)" ::: "memory");
    else            asm volatile("s_waitcnt vmcnt(0)" ::: "memory");
    __builtin_amdgcn_s_barrier();
    __builtin_amdgcn_sched_barrier(0);

    if (t + 2 < nt) STAGE(t + 2, s2);

    s16x8 af[4], bfr[4];
#pragma unroll
    for (int i = 0; i < 4; ++i)
      af[i] = *(const s16x8*)(&As[cur][(wr + i * 16 + fr) * 32 + rdA]);
#pragma unroll
    for (int j = 0; j < 4; ++j)
      bfr[j] = *(const s16x8*)(&Bs[cur][(wc + j * 16 + fr) * 32 + rdA]);
    __builtin_amdgcn_s_setprio(1);
#pragma unroll
    for (int i = 0; i < 4; ++i)
#pragma unroll
      for (int j = 0; j < 4; ++j)
        acc[i][j] = __builtin_amdgcn_mfma_f32_16x16x32_bf16(af[i], bfr[j], acc[i][j], 0, 0, 0);
    __builtin_amdgcn_s_setprio(0);

    cur += 1; if (cur >= 3) cur -= 3;
    s2  += 1; if (s2  >= 3) s2  -= 3;
  }

  // C/D layout: col = lane&15, row = (lane>>4)*4 + reg
  const int crow_base = m0 + wr + kg * 4;
  const int ccol_base = n0 + wc + fr;
  const bool addb = (bias != nullptr) && (blockIdx.z == 0);
#pragma unroll
  for (int j = 0; j < 4; ++j) {
    int col = ccol_base + j * 16;
    float bv = addb ? bias[col] : 0.f;
#pragma unroll
    for (int i = 0; i < 4; ++i)
#pragma unroll
      for (int r = 0; r < 4; ++r) {
        int grow = crow_base + i * 16 + r;
        if (grow < Mdim) atomicAdd(&C[(size_t)grow * Ndim + col], acc[i][j][r] + bv);
      }
  }
}

// ---- Local attention: one wave per (b,i,h), fp32 qkv input -----------------
// Lane mapping: jj = lane>>2 (window pos 0..15), ds = lane&3 (16-dim segment).
// QK: 16 FMA + 2 shfl; softmax: 8 shfl + one v_exp; PV: e*v on segments,
// LDS transpose [16][68], lane=d sums 16 rows.
__global__ __launch_bounds__(256)
void local_attn(const float* __restrict__ qkv, ushort* __restrict__ ao) {
  __shared__ float plds[4][16][68];   // 17.4 KB
  const int wv = threadIdx.x >> 6;
  const int gw = blockIdx.x * 4 + wv;
  if (gw >= B_SZ * HEADS * N_SEQ) return;
  const int lane = threadIdx.x & 63;
  const int jj = lane >> 2;
  const int ds = lane & 3;
  const int h = gw % HEADS;
  const int t = gw / HEADS;
  const int i = t % N_SEQ;
  const int b = t / N_SEQ;
  const int row = b * N_SEQ + i;
  const size_t stride = 3 * DIMC;

  int j0 = i - WIN; if (j0 < 0) j0 = 0;
  int j1 = i + WIN; if (j1 > N_SEQ) j1 = N_SEQ;   // [j0, j1)
  const int j = j0 + jj;
  const bool ok = (j < j1);
  const int jc = ok ? j : (j1 - 1);

  // q segment (16 dims at ds*16), scale folded
  f32x4 q0, q1, q2, q3;
  {
    const float* qp = qkv + (size_t)row * stride + h * HD + ds * 16;
    q0 = *(const f32x4*)(qp);
    q1 = *(const f32x4*)(qp + 4);
    q2 = *(const f32x4*)(qp + 8);
    q3 = *(const f32x4*)(qp + 12);
#pragma unroll
    for (int e = 0; e < 4; ++e) {
      q0[e] *= 0.125f; q1[e] *= 0.125f; q2[e] *= 0.125f; q3[e] *= 0.125f;
    }
  }

  // dot(q, k[jc]) on this lane's segment
  float s = 0.f;
  {
    const float* kp = qkv + (size_t)(b * N_SEQ + jc) * stride + DIMC + h * HD + ds * 16;
    f32x4 k0 = *(const f32x4*)(kp);
    f32x4 k1 = *(const f32x4*)(kp + 4);
    f32x4 k2 = *(const f32x4*)(kp + 8);
    f32x4 k3 = *(const f32x4*)(kp + 12);
#pragma unroll
    for (int e = 0; e < 4; ++e) {
      s += q0[e] * k0[e];
      s += q1[e] * k1[e];
      s += q2[e] * k2[e];
      s += q3[e] * k3[e];
    }
  }
  s += __shfl_xor(s, 1);
  s += __shfl_xor(s, 2);     // full dot, replicated across ds

  {
    float d = fabsf((float)(i - j));
    float m = 1.0f - d * 0.0625f;   // (W - d/2)/W
    s = ok ? s * m : -INFINITY;
  }

  // softmax across jj (lane bits 2..5)
  float mx = s;
  mx = fmaxf(mx, __shfl_xor(mx, 4));
  mx = fmaxf(mx, __shfl_xor(mx, 8));
  mx = fmaxf(mx, __shfl_xor(mx, 16));
  mx = fmaxf(mx, __shfl_xor(mx, 32));
  float e = __expf(s - mx);
  float sum = e;
  sum += __shfl_xor(sum, 4);
  sum += __shfl_xor(sum, 8);
  sum += __shfl_xor(sum, 16);
  sum += __shfl_xor(sum, 32);
  const float inv = 1.f / sum;

  // PV: e * v[jc] segment -> LDS transpose
  {
    const float* vp = qkv + (size_t)(b * N_SEQ + jc) * stride + 2 * DIMC + h * HD + ds * 16;
    f32x4 v0 = *(const f32x4*)(vp);
    f32x4 v1 = *(const f32x4*)(vp + 4);
    f32x4 v2 = *(const f32x4*)(vp + 8);
    f32x4 v3 = *(const f32x4*)(vp + 12);
    const float ee = ok ? e : 0.f;   // clamped lanes contribute 0
    f32x4 w0, w1, w2, w3;
#pragma unroll
    for (int g = 0; g < 4; ++g) {
      w0[g] = ee * v0[g]; w1[g] = ee * v1[g];
      w2[g] = ee * v2[g]; w3[g] = ee * v3[g];
    }
    *(f32x4*)&plds[wv][jj][ds * 16]      = w0;
    *(f32x4*)&plds[wv][jj][ds * 16 + 4]  = w1;
    *(f32x4*)&plds[wv][jj][ds * 16 + 8]  = w2;
    *(f32x4*)&plds[wv][jj][ds * 16 + 12] = w3;
  }
  asm volatile("s_waitcnt lgkmcnt(0)" ::: "memory");
  __builtin_amdgcn_sched_barrier(0);

  float o = 0.f;
#pragma unroll
  for (int q = 0; q < 16; ++q) o += plds[wv][q][lane];
  ao[(size_t)row * DIMC + h * HD + lane] = f2bf(o * inv);
}

// ----------------------------------------------------------------------------
extern "C" void kernel_launch(void* const* d_in, const int* in_sizes, int n_in,
                              void* d_out, int out_size, void* d_ws, size_t ws_size,
                              hipStream_t stream) {
  const float* x      = (const float*)d_in[0];
  const float* qkv_w  = (const float*)d_in[1];
  const float* proj_w = (const float*)d_in[2];
  const float* proj_b = (const float*)d_in[3];
  float* out = (float*)d_out;

  // ws layout: bf16 inputs for GEMMs + fp32 qkv accumulator + bf16 ao
  char* p = (char*)d_ws;
  ushort* x_bf    = (ushort*)p;  p += (size_t)M_PAD * DIMC * 2;            // 3.7 MB
  ushort* qkvw_bf = (ushort*)p;  p += (size_t)3 * DIMC * DIMC * 2;         // 25.2 MB
  ushort* projw_bf= (ushort*)p;  p += (size_t)DIMC * DIMC * 2;             // 8.4 MB
  float*  qkv_f   = (float*)p;   p += (size_t)M_ROWS * 3 * DIMC * 4;       // 19.4 MB
  ushort* ao_bf   = (ushort*)p;                                            // 3.7 MB

  dim3 blk(256);

  // conversions + zero qkv_f and out (both atomic-accumulated later)
  {
    int total = NX + NQ + NP + NZQ + NZO;
    cvt_all<<<dim3((total + 255) / 256), blk, 0, stream>>>(
        x, qkv_w, proj_w, x_bf, qkvw_bf, projw_bf, qkv_f, out);
  }

  // QKV GEMM: split-K=2, grid (7,48,2) = 672 blocks, fp32 atomic accumulate
  gemm_bt_atomic<<<dim3(M_PAD / 128, (3 * DIMC) / 128, 2), blk, 0, stream>>>(
      x_bf, qkvw_bf, qkv_f, nullptr, M_ROWS, 3 * DIMC, DIMC, DIMC / 2);

  // Local attention on summed fp32 qkv -> ao bf16
  int total_waves = B_SZ * HEADS * N_SEQ;  // 25216
  local_attn<<<dim3((total_waves + 3) / 4), blk, 0, stream>>>(qkv_f, ao_bf);

  // Proj GEMM: split-K=2, grid (7,16,2) = 224 blocks, fp32 atomic accumulate
  // into zeroed d_out; bias added once by z==0 blocks.
  gemm_bt_atomic<<<dim3(M_PAD / 128, DIMC / 128, 2), blk, 0, stream>>>(
      ao_bf, projw_bf, out, proj_b, M_ROWS, DIMC, DIMC, DIMC / 2);
}

// Round 12
// 93.516 us; speedup vs baseline: 1.4758x; 1.4758x over previous
//
#include <hip/hip_runtime.h>
#include <math.h>

#define B_SZ   4
#define N_SEQ  197
#define DIMC   2048
#define HEADS  32
#define HD     64
#define WIN    8
#define M_ROWS (B_SZ * N_SEQ)   // 788
#define M_PAD  896               // 7 * 128

using f32x4 = __attribute__((ext_vector_type(4))) float;
using s16x8 = __attribute__((ext_vector_type(8))) short;

__device__ inline ushort f2bf(float f) {
  uint x = __float_as_uint(f);
  uint r = (x + 0x7fffu + ((x >> 16) & 1u)) >> 16;  // RNE
  return (ushort)r;
}
__device__ inline float bf2f(ushort u) {
  return __uint_as_float(((uint)u) << 16);
}

__device__ inline void gload16(const ushort* g, ushort* l) {
  __builtin_amdgcn_global_load_lds(
      (const __attribute__((address_space(1))) unsigned int*)g,
      (__attribute__((address_space(3))) unsigned int*)l, 16, 0, 0);
}

// ---------- fused fp32 -> bf16 conversion (x, qkv_w, proj_w) ----------------
#define NX (M_ROWS * DIMC / 8)        // 201728
#define NQ (3 * DIMC * DIMC / 8)      // 1572864
#define NP (DIMC * DIMC / 8)          // 524288

__global__ __launch_bounds__(256)
void cvt_all(const float* __restrict__ x,  const float* __restrict__ qw,
             const float* __restrict__ pw, ushort* __restrict__ xb,
             ushort* __restrict__ qwb, ushort* __restrict__ pwb) {
  int i = blockIdx.x * 256 + threadIdx.x;
  const float* src; ushort* dst; int idx;
  if (i < NX)                { src = x;  dst = xb;  idx = i; }
  else if (i < NX + NQ)      { src = qw; dst = qwb; idx = i - NX; }
  else if (i < NX + NQ + NP) { src = pw; dst = pwb; idx = i - NX - NQ; }
  else return;
  f32x4 a = ((const f32x4*)src)[2 * idx];
  f32x4 b = ((const f32x4*)src)[2 * idx + 1];
  ushort4 u0, u1;
  u0.x = f2bf(a.x); u0.y = f2bf(a.y); u0.z = f2bf(a.z); u0.w = f2bf(a.w);
  u1.x = f2bf(b.x); u1.y = f2bf(b.y); u1.z = f2bf(b.z); u1.w = f2bf(b.w);
  ((ushort4*)dst)[2 * idx]     = u0;
  ((ushort4*)dst)[2 * idx + 1] = u1;
}

// ---- GEMM: Cpart[z] = A(bf16,MxK) @ Bw(bf16,NxK)^T over K-slice z ----------
// 128x128 tile, 4 waves, 64x64/wave: 16 MFMA + 8 ds_read_b128 per K-step.
// Depth-2 counted-vmcnt pipeline over 3 LDS buffers. 2-way slot swizzle.
// Output: bf16 partial slice at Cout + z*Mdim*Ndim (guarded rows < Mdim).
__global__ __launch_bounds__(256, 3)
void gemm_bt_bf16(const ushort* __restrict__ A, const ushort* __restrict__ Bw,
                  ushort* __restrict__ Cout,
                  int Mdim, int Ndim, int Kfull, int Ksplit) {
  __shared__ ushort As[3][128 * 32];
  __shared__ ushort Bs[3][128 * 32];
  const int tid  = threadIdx.x;
  const int lane = tid & 63;
  const int wave = tid >> 6;

  const int nwg  = gridDim.x * gridDim.y;
  const int phys = blockIdx.y * gridDim.x + blockIdx.x;
  const int cpx  = nwg >> 3;
  const int lg   = (phys & 7) * cpx + (phys >> 3);
  const int m0 = (lg % gridDim.x) * 128;
  const int n0 = (lg / gridDim.x) * 128;
  const int koff = blockIdx.z * Ksplit;
  ushort* C = Cout + (size_t)blockIdx.z * Mdim * Ndim;

  const int wr = (wave >> 1) * 64;
  const int wc = (wave & 1) * 64;
  const int fr = lane & 15;
  const int kg = lane >> 4;
  const int srow = lane >> 2;
  const int scol = ((lane & 3) ^ ((srow >> 1) & 3)) * 8;
  const int rdA  = (kg ^ ((fr >> 1) & 3)) * 8;

  f32x4 acc[4][4];
#pragma unroll
  for (int i = 0; i < 4; ++i)
#pragma unroll
    for (int j = 0; j < 4; ++j)
      acc[i][j] = (f32x4){0.f, 0.f, 0.f, 0.f};

  const ushort* Asrc0 = A  + (size_t)(m0 + wave * 32 + srow)      * Kfull + koff + scol;
  const ushort* Asrc1 = A  + (size_t)(m0 + wave * 32 + 16 + srow) * Kfull + koff + scol;
  const ushort* Bsrc0 = Bw + (size_t)(n0 + wave * 32 + srow)      * Kfull + koff + scol;
  const ushort* Bsrc1 = Bw + (size_t)(n0 + wave * 32 + 16 + srow) * Kfull + koff + scol;

  const int nt = Ksplit >> 5;

  auto STAGE = [&](int kk, int b) {
    const int k = kk << 5;
    gload16(Asrc0 + k, &As[b][wave * 1024]);
    gload16(Asrc1 + k, &As[b][wave * 1024 + 512]);
    gload16(Bsrc0 + k, &Bs[b][wave * 1024]);
    gload16(Bsrc1 + k, &Bs[b][wave * 1024 + 512]);
  };

  STAGE(0, 0);
  STAGE(1, 1);

  int cur = 0, s2 = 2;
  for (int t = 0; t < nt; ++t) {
    if (t < nt - 1) asm volatile("s_waitcnt vmcnt(4)" ::: "memory");
    else            asm volatile("s_waitcnt vmcnt(0)" ::: "memory");
    __builtin_amdgcn_s_barrier();
    __builtin_amdgcn_sched_barrier(0);

    if (t + 2 < nt) STAGE(t + 2, s2);

    s16x8 af[4], bfr[4];
#pragma unroll
    for (int i = 0; i < 4; ++i)
      af[i] = *(const s16x8*)(&As[cur][(wr + i * 16 + fr) * 32 + rdA]);
#pragma unroll
    for (int j = 0; j < 4; ++j)
      bfr[j] = *(const s16x8*)(&Bs[cur][(wc + j * 16 + fr) * 32 + rdA]);
    __builtin_amdgcn_s_setprio(1);
#pragma unroll
    for (int i = 0; i < 4; ++i)
#pragma unroll
      for (int j = 0; j < 4; ++j)
        acc[i][j] = __builtin_amdgcn_mfma_f32_16x16x32_bf16(af[i], bfr[j], acc[i][j], 0, 0, 0);
    __builtin_amdgcn_s_setprio(0);

    cur += 1; if (cur >= 3) cur -= 3;
    s2  += 1; if (s2  >= 3) s2  -= 3;
  }

  const int crow_base = m0 + wr + kg * 4;
  const int ccol_base = n0 + wc + fr;
#pragma unroll
  for (int j = 0; j < 4; ++j) {
    int col = ccol_base + j * 16;
#pragma unroll
    for (int i = 0; i < 4; ++i)
#pragma unroll
      for (int r = 0; r < 4; ++r) {
        int grow = crow_base + i * 16 + r;
        if (grow < Mdim) C[(size_t)grow * Ndim + col] = f2bf(acc[i][j][r]);
      }
  }
}

// ---- qkv partial reduce + head-major transpose -----------------------------
// in: two bf16 slices (788 x 6144, col = tensor*2048 + h*64 + d)
// out: bf16 [tensor][h][row][64] -> a head's K window is a contiguous block.
#define NGQ (M_ROWS * 3 * DIMC / 8)   // 605184 granules of 8
__global__ __launch_bounds__(256)
void reduce_qkv_t(const ushort* __restrict__ p0, const ushort* __restrict__ p1,
                  ushort* __restrict__ qt) {
  int i = blockIdx.x * 256 + threadIdx.x;
  if (i >= NGQ) return;
  const int row = i / 768;          // 6144/8 granules per row
  const int c8  = i - row * 768;
  const int col = c8 * 8;
  const int tns = col >> 11;        // 0..2
  const int h   = (col >> 6) & 31;
  const int d   = col & 63;
  s16x8 a = *(const s16x8*)(p0 + (size_t)i * 8);
  s16x8 b = *(const s16x8*)(p1 + (size_t)i * 8);
  s16x8 r;
#pragma unroll
  for (int e = 0; e < 8; ++e)
    r[e] = (short)f2bf(bf2f((ushort)a[e]) + bf2f((ushort)b[e]));
  *(s16x8*)(qt + ((size_t)(tns * HEADS + h) * M_ROWS + row) * HD + d) = r;
}

// ---- Local attention: one wave per (b,i,h), head-major bf16 qkv ------------
// Lane mapping: jj = lane>>2 (window pos 0..15), ds = lane&3 (16-dim segment).
// K/V window rows are contiguous (row*64 within [h] block). QK: 16 FMA +
// 2 shfl; softmax: 8 shfl + v_exp; PV: LDS transpose [16][68], lane=d sums.
__global__ __launch_bounds__(256)
void local_attn(const ushort* __restrict__ qt, ushort* __restrict__ ao) {
  __shared__ float plds[4][16][68];   // 17.4 KB
  const int wv = threadIdx.x >> 6;
  const int gw = blockIdx.x * 4 + wv;
  if (gw >= B_SZ * HEADS * N_SEQ) return;
  const int lane = threadIdx.x & 63;
  const int jj = lane >> 2;
  const int ds = lane & 3;
  const int h = gw % HEADS;
  const int t = gw / HEADS;
  const int i = t % N_SEQ;
  const int b = t / N_SEQ;
  const int row = b * N_SEQ + i;

  const ushort* qb = qt + (size_t)h * M_ROWS * HD;                 // q block
  const ushort* kb = qt + (size_t)(HEADS + h) * M_ROWS * HD;       // k block
  const ushort* vb = qt + (size_t)(2 * HEADS + h) * M_ROWS * HD;   // v block

  int j0 = i - WIN; if (j0 < 0) j0 = 0;
  int j1 = i + WIN; if (j1 > N_SEQ) j1 = N_SEQ;   // [j0, j1)
  const int j = j0 + jj;
  const bool ok = (j < j1);
  const int jc = ok ? j : (j1 - 1);
  const int krow = b * N_SEQ + jc;

  // q segment (16 dims at ds*16) — whole wave shares one 128B row
  float qs[16];
  {
    const ushort* qp = qb + (size_t)row * HD + ds * 16;
    s16x8 a0 = *(const s16x8*)(qp);
    s16x8 a1 = *(const s16x8*)(qp + 8);
#pragma unroll
    for (int e = 0; e < 8; ++e) {
      qs[e]     = bf2f((ushort)a0[e]);
      qs[8 + e] = bf2f((ushort)a1[e]);
    }
  }

  // dot(q, k[jc]) on this lane's segment — window rows contiguous (2KB)
  float s = 0.f;
  {
    const ushort* kp = kb + (size_t)krow * HD + ds * 16;
    s16x8 a0 = *(const s16x8*)(kp);
    s16x8 a1 = *(const s16x8*)(kp + 8);
#pragma unroll
    for (int e = 0; e < 8; ++e) {
      s += qs[e]     * bf2f((ushort)a0[e]);
      s += qs[8 + e] * bf2f((ushort)a1[e]);
    }
  }
  s += __shfl_xor(s, 1);
  s += __shfl_xor(s, 2);     // full dot, replicated across ds

  {
    float d = fabsf((float)(i - j));
    float m = 1.0f - d * 0.0625f;   // (W - d/2)/W
    s = ok ? s * 0.125f * m : -INFINITY;   // scale folded once
  }

  // softmax across jj (lane bits 2..5)
  float mx = s;
  mx = fmaxf(mx, __shfl_xor(mx, 4));
  mx = fmaxf(mx, __shfl_xor(mx, 8));
  mx = fmaxf(mx, __shfl_xor(mx, 16));
  mx = fmaxf(mx, __shfl_xor(mx, 32));
  float e = __expf(s - mx);
  float sum = e;
  sum += __shfl_xor(sum, 4);
  sum += __shfl_xor(sum, 8);
  sum += __shfl_xor(sum, 16);
  sum += __shfl_xor(sum, 32);
  const float inv = 1.f / sum;

  // PV: e * v[jc] segment -> LDS transpose, then lane=d sums 16 rows
  {
    const ushort* vp = vb + (size_t)krow * HD + ds * 16;
    s16x8 a0 = *(const s16x8*)(vp);
    s16x8 a1 = *(const s16x8*)(vp + 8);
    const float ee = ok ? e : 0.f;   // clamped lanes contribute 0
    f32x4 w0, w1, w2, w3;
#pragma unroll
    for (int g = 0; g < 4; ++g) {
      w0[g] = ee * bf2f((ushort)a0[g]);
      w1[g] = ee * bf2f((ushort)a0[4 + g]);
      w2[g] = ee * bf2f((ushort)a1[g]);
      w3[g] = ee * bf2f((ushort)a1[4 + g]);
    }
    *(f32x4*)&plds[wv][jj][ds * 16]      = w0;
    *(f32x4*)&plds[wv][jj][ds * 16 + 4]  = w1;
    *(f32x4*)&plds[wv][jj][ds * 16 + 8]  = w2;
    *(f32x4*)&plds[wv][jj][ds * 16 + 12] = w3;
  }
  asm volatile("s_waitcnt lgkmcnt(0)" ::: "memory");
  __builtin_amdgcn_sched_barrier(0);

  float o = 0.f;
#pragma unroll
  for (int q = 0; q < 16; ++q) o += plds[wv][q][lane];
  ao[(size_t)row * DIMC + h * HD + lane] = f2bf(o * inv);
}

// ---- proj split-K reduce: out = parts[0] + parts[1] + bias (fp32) ----------
#define NR8 (M_ROWS * DIMC / 8)   // 201728
__global__ __launch_bounds__(256)
void reduce2_bias(const ushort* __restrict__ parts, const float* __restrict__ bias,
                  float* __restrict__ out) {
  int i = blockIdx.x * 256 + threadIdx.x;
  if (i >= NR8) return;
  const size_t slice = (size_t)M_ROWS * DIMC;
  float a[8];
#pragma unroll
  for (int e = 0; e < 8; ++e) a[e] = 0.f;
#pragma unroll
  for (int z = 0; z < 2; ++z) {
    s16x8 v = *(const s16x8*)(parts + z * slice + (size_t)i * 8);
#pragma unroll
    for (int e = 0; e < 8; ++e) a[e] += bf2f((ushort)v[e]);
  }
  const int col = (i * 8) & (DIMC - 1);
  f32x4 b0 = *(const f32x4*)(bias + col);
  f32x4 b1 = *(const f32x4*)(bias + col + 4);
  f32x4 o0 = {a[0] + b0.x, a[1] + b0.y, a[2] + b0.z, a[3] + b0.w};
  f32x4 o1 = {a[4] + b1.x, a[5] + b1.y, a[6] + b1.z, a[7] + b1.w};
  ((f32x4*)out)[2 * i]     = o0;
  ((f32x4*)out)[2 * i + 1] = o1;
}

// ----------------------------------------------------------------------------
extern "C" void kernel_launch(void* const* d_in, const int* in_sizes, int n_in,
                              void* d_out, int out_size, void* d_ws, size_t ws_size,
                              hipStream_t stream) {
  const float* x      = (const float*)d_in[0];
  const float* qkv_w  = (const float*)d_in[1];
  const float* proj_w = (const float*)d_in[2];
  const float* proj_b = (const float*)d_in[3];
  float* out = (float*)d_out;

  // ws layout (bf16; pad rows of x_bf/ao_bf hold poison, read only for pad
  // output rows whose stores are masked)
  char* p = (char*)d_ws;
  ushort* x_bf    = (ushort*)p;  p += (size_t)M_PAD * DIMC * 2;            // 3.7 MB
  ushort* qkvw_bf = (ushort*)p;  p += (size_t)3 * DIMC * DIMC * 2;         // 25.2 MB
  ushort* projw_bf= (ushort*)p;  p += (size_t)DIMC * DIMC * 2;             // 8.4 MB
  ushort* qkv_p   = (ushort*)p;  p += (size_t)2 * M_ROWS * 3 * DIMC * 2;   // 19.4 MB
  ushort* qkv_t   = (ushort*)p;  p += (size_t)M_ROWS * 3 * DIMC * 2;       // 9.7 MB
  ushort* ao_bf   = (ushort*)p;  p += (size_t)M_PAD * DIMC * 2;            // 3.7 MB
  ushort* proj_p  = (ushort*)p;                                            // 6.5 MB

  dim3 blk(256);

  // fp32 -> bf16 conversions
  {
    int total = NX + NQ + NP;
    cvt_all<<<dim3((total + 255) / 256), blk, 0, stream>>>(
        x, qkv_w, proj_w, x_bf, qkvw_bf, projw_bf);
  }

  // QKV GEMM: split-K=2, grid (7,48,2) = 672 blocks, bf16 partial slices
  gemm_bt_bf16<<<dim3(M_PAD / 128, (3 * DIMC) / 128, 2), blk, 0, stream>>>(
      x_bf, qkvw_bf, qkv_p, M_ROWS, 3 * DIMC, DIMC, DIMC / 2);

  // Reduce qkv partials + transpose to head-major [tensor][h][row][64]
  reduce_qkv_t<<<dim3((NGQ + 255) / 256), blk, 0, stream>>>(
      qkv_p, qkv_p + (size_t)M_ROWS * 3 * DIMC, qkv_t);

  // Local attention on head-major qkv -> ao bf16
  int total_waves = B_SZ * HEADS * N_SEQ;  // 25216
  local_attn<<<dim3((total_waves + 3) / 4), blk, 0, stream>>>(qkv_t, ao_bf);

  // Proj GEMM: split-K=2, grid (7,16,2) = 224 blocks, bf16 partial slices
  gemm_bt_bf16<<<dim3(M_PAD / 128, DIMC / 128, 2), blk, 0, stream>>>(
      ao_bf, projw_bf, proj_p, M_ROWS, DIMC, DIMC, DIMC / 2);

  // Reduce 2 proj partials + bias -> fp32 d_out
  reduce2_bias<<<dim3((NR8 + 255) / 256), blk, 0, stream>>>(proj_p, proj_b, out);
}

// Round 13
// 87.655 us; speedup vs baseline: 1.5745x; 1.0669x over previous
//
#include <hip/hip_runtime.h>
#include <math.h>

#define B_SZ   4
#define N_SEQ  197
#define DIMC   2048
#define HEADS  32
#define HD     64
#define WIN    8
#define M_ROWS (B_SZ * N_SEQ)   // 788
#define M_PAD  896               // 7 * 128

using f32x4 = __attribute__((ext_vector_type(4))) float;
using s16x8 = __attribute__((ext_vector_type(8))) short;

__device__ inline ushort f2bf(float f) {
  uint x = __float_as_uint(f);
  uint r = (x + 0x7fffu + ((x >> 16) & 1u)) >> 16;  // RNE
  return (ushort)r;
}
__device__ inline float bf2f(ushort u) {
  return __uint_as_float(((uint)u) << 16);
}

__device__ inline void gload16(const ushort* g, ushort* l) {
  __builtin_amdgcn_global_load_lds(
      (const __attribute__((address_space(1))) unsigned int*)g,
      (__attribute__((address_space(3))) unsigned int*)l, 16, 0, 0);
}

// ---------- fused fp32 -> bf16 conversion (x, qkv_w, proj_w) ----------------
#define NX (M_ROWS * DIMC / 8)        // 201728
#define NQ (3 * DIMC * DIMC / 8)      // 1572864
#define NP (DIMC * DIMC / 8)          // 524288

__global__ __launch_bounds__(256)
void cvt_all(const float* __restrict__ x,  const float* __restrict__ qw,
             const float* __restrict__ pw, ushort* __restrict__ xb,
             ushort* __restrict__ qwb, ushort* __restrict__ pwb) {
  int i = blockIdx.x * 256 + threadIdx.x;
  const float* src; ushort* dst; int idx;
  if (i < NX)                { src = x;  dst = xb;  idx = i; }
  else if (i < NX + NQ)      { src = qw; dst = qwb; idx = i - NX; }
  else if (i < NX + NQ + NP) { src = pw; dst = pwb; idx = i - NX - NQ; }
  else return;
  f32x4 a = ((const f32x4*)src)[2 * idx];
  f32x4 b = ((const f32x4*)src)[2 * idx + 1];
  ushort4 u0, u1;
  u0.x = f2bf(a.x); u0.y = f2bf(a.y); u0.z = f2bf(a.z); u0.w = f2bf(a.w);
  u1.x = f2bf(b.x); u1.y = f2bf(b.y); u1.z = f2bf(b.z); u1.w = f2bf(b.w);
  ((ushort4*)dst)[2 * idx]     = u0;
  ((ushort4*)dst)[2 * idx + 1] = u1;
}

// ---- GEMM: Cpart[z] = A(bf16,MxK) @ Bw(bf16,NxK)^T over K-slice z ----------
// 128x128 tile, 4 waves, 64x64/wave: 16 MFMA + 8 ds_read_b128 per K-step.
// Depth-2 counted-vmcnt pipeline over 3 LDS buffers. 2-way slot swizzle.
// Output: bf16 partial slice at Cout + z*Mdim*Ndim (guarded rows < Mdim).
__global__ __launch_bounds__(256, 3)
void gemm_bt_bf16(const ushort* __restrict__ A, const ushort* __restrict__ Bw,
                  ushort* __restrict__ Cout,
                  int Mdim, int Ndim, int Kfull, int Ksplit) {
  __shared__ ushort As[3][128 * 32];
  __shared__ ushort Bs[3][128 * 32];
  const int tid  = threadIdx.x;
  const int lane = tid & 63;
  const int wave = tid >> 6;

  const int nwg  = gridDim.x * gridDim.y;
  const int phys = blockIdx.y * gridDim.x + blockIdx.x;
  const int cpx  = nwg >> 3;
  const int lg   = (phys & 7) * cpx + (phys >> 3);
  const int m0 = (lg % gridDim.x) * 128;
  const int n0 = (lg / gridDim.x) * 128;
  const int koff = blockIdx.z * Ksplit;
  ushort* C = Cout + (size_t)blockIdx.z * Mdim * Ndim;

  const int wr = (wave >> 1) * 64;
  const int wc = (wave & 1) * 64;
  const int fr = lane & 15;
  const int kg = lane >> 4;
  const int srow = lane >> 2;
  const int scol = ((lane & 3) ^ ((srow >> 1) & 3)) * 8;
  const int rdA  = (kg ^ ((fr >> 1) & 3)) * 8;

  f32x4 acc[4][4];
#pragma unroll
  for (int i = 0; i < 4; ++i)
#pragma unroll
    for (int j = 0; j < 4; ++j)
      acc[i][j] = (f32x4){0.f, 0.f, 0.f, 0.f};

  const ushort* Asrc0 = A  + (size_t)(m0 + wave * 32 + srow)      * Kfull + koff + scol;
  const ushort* Asrc1 = A  + (size_t)(m0 + wave * 32 + 16 + srow) * Kfull + koff + scol;
  const ushort* Bsrc0 = Bw + (size_t)(n0 + wave * 32 + srow)      * Kfull + koff + scol;
  const ushort* Bsrc1 = Bw + (size_t)(n0 + wave * 32 + 16 + srow) * Kfull + koff + scol;

  const int nt = Ksplit >> 5;

  auto STAGE = [&](int kk, int b) {
    const int k = kk << 5;
    gload16(Asrc0 + k, &As[b][wave * 1024]);
    gload16(Asrc1 + k, &As[b][wave * 1024 + 512]);
    gload16(Bsrc0 + k, &Bs[b][wave * 1024]);
    gload16(Bsrc1 + k, &Bs[b][wave * 1024 + 512]);
  };

  STAGE(0, 0);
  STAGE(1, 1);

  int cur = 0, s2 = 2;
  for (int t = 0; t < nt; ++t) {
    if (t < nt - 1) asm volatile("s_waitcnt vmcnt(4)" ::: "memory");
    else            asm volatile("s_waitcnt vmcnt(0)" ::: "memory");
    __builtin_amdgcn_s_barrier();
    __builtin_amdgcn_sched_barrier(0);

    if (t + 2 < nt) STAGE(t + 2, s2);

    s16x8 af[4], bfr[4];
#pragma unroll
    for (int i = 0; i < 4; ++i)
      af[i] = *(const s16x8*)(&As[cur][(wr + i * 16 + fr) * 32 + rdA]);
#pragma unroll
    for (int j = 0; j < 4; ++j)
      bfr[j] = *(const s16x8*)(&Bs[cur][(wc + j * 16 + fr) * 32 + rdA]);
    __builtin_amdgcn_s_setprio(1);
#pragma unroll
    for (int i = 0; i < 4; ++i)
#pragma unroll
      for (int j = 0; j < 4; ++j)
        acc[i][j] = __builtin_amdgcn_mfma_f32_16x16x32_bf16(af[i], bfr[j], acc[i][j], 0, 0, 0);
    __builtin_amdgcn_s_setprio(0);

    cur += 1; if (cur >= 3) cur -= 3;
    s2  += 1; if (s2  >= 3) s2  -= 3;
  }

  const int crow_base = m0 + wr + kg * 4;
  const int ccol_base = n0 + wc + fr;
#pragma unroll
  for (int j = 0; j < 4; ++j) {
    int col = ccol_base + j * 16;
#pragma unroll
    for (int i = 0; i < 4; ++i)
#pragma unroll
      for (int r = 0; r < 4; ++r) {
        int grow = crow_base + i * 16 + r;
        if (grow < Mdim) C[(size_t)grow * Ndim + col] = f2bf(acc[i][j][r]);
      }
  }
}

// ---- Local attention + qkv split-K reduce: one wave per (b,i,h) ------------
// Lane mapping: jj = lane>>2 (window pos 0..15), ds = lane&3 (16-dim segment).
// V loads hoisted before the softmax shuffle chain (latency overlap); scale
// folded into one post-dot multiply.
__global__ __launch_bounds__(256)
void local_attn(const ushort* __restrict__ p0, const ushort* __restrict__ p1,
                ushort* __restrict__ ao) {
  __shared__ float plds[4][16][68];   // 17.4 KB
  const int wv = threadIdx.x >> 6;
  const int gw = blockIdx.x * 4 + wv;
  if (gw >= B_SZ * HEADS * N_SEQ) return;
  const int lane = threadIdx.x & 63;
  const int jj = lane >> 2;
  const int ds = lane & 3;
  const int h = gw % HEADS;
  const int t = gw / HEADS;
  const int i = t % N_SEQ;
  const int b = t / N_SEQ;
  const int row = b * N_SEQ + i;
  const size_t stride = 3 * DIMC;

  int j0 = i - WIN; if (j0 < 0) j0 = 0;
  int j1 = i + WIN; if (j1 > N_SEQ) j1 = N_SEQ;   // [j0, j1)
  const int j = j0 + jj;
  const bool ok = (j < j1);
  const int jc = ok ? j : (j1 - 1);
  const size_t kvbase = (size_t)(b * N_SEQ + jc) * stride + h * HD + ds * 16;

  // issue V loads FIRST (independent of the whole softmax chain)
  const ushort* vp0 = p0 + kvbase + 2 * DIMC;
  const ushort* vp1 = p1 + kvbase + 2 * DIMC;
  s16x8 va0 = *(const s16x8*)(vp0);
  s16x8 va1 = *(const s16x8*)(vp0 + 8);
  s16x8 vb0 = *(const s16x8*)(vp1);
  s16x8 vb1 = *(const s16x8*)(vp1 + 8);

  // q segment (16 dims at ds*16), partials summed; scale folded post-dot
  float qs[16];
  {
    const size_t qi = (size_t)row * stride + h * HD + ds * 16;
    s16x8 a0 = *(const s16x8*)(p0 + qi);
    s16x8 a1 = *(const s16x8*)(p0 + qi + 8);
    s16x8 b0 = *(const s16x8*)(p1 + qi);
    s16x8 b1 = *(const s16x8*)(p1 + qi + 8);
#pragma unroll
    for (int e = 0; e < 8; ++e) {
      qs[e]     = bf2f((ushort)a0[e]) + bf2f((ushort)b0[e]);
      qs[8 + e] = bf2f((ushort)a1[e]) + bf2f((ushort)b1[e]);
    }
  }

  // dot(q, k[jc]) on this lane's segment
  float s;
  {
    const ushort* kp0 = p0 + kvbase + DIMC;
    const ushort* kp1 = p1 + kvbase + DIMC;
    s16x8 a0 = *(const s16x8*)(kp0);
    s16x8 a1 = *(const s16x8*)(kp0 + 8);
    s16x8 b0 = *(const s16x8*)(kp1);
    s16x8 b1 = *(const s16x8*)(kp1 + 8);
    float acc = 0.f;
#pragma unroll
    for (int e = 0; e < 8; ++e) {
      acc += qs[e]     * (bf2f((ushort)a0[e]) + bf2f((ushort)b0[e]));
      acc += qs[8 + e] * (bf2f((ushort)a1[e]) + bf2f((ushort)b1[e]));
    }
    s = acc;
  }
  s += __shfl_xor(s, 1);
  s += __shfl_xor(s, 2);     // full dot, replicated across ds

  {
    float d = fabsf((float)(i - j));
    float m = 1.0f - d * 0.0625f;          // (W - d/2)/W
    s = ok ? s * (0.125f * m) : -INFINITY; // scale folded once
  }

  // softmax across jj (lane bits 2..5)
  float mx = s;
  mx = fmaxf(mx, __shfl_xor(mx, 4));
  mx = fmaxf(mx, __shfl_xor(mx, 8));
  mx = fmaxf(mx, __shfl_xor(mx, 16));
  mx = fmaxf(mx, __shfl_xor(mx, 32));
  float e = __expf(s - mx);
  float sum = e;
  sum += __shfl_xor(sum, 4);
  sum += __shfl_xor(sum, 8);
  sum += __shfl_xor(sum, 16);
  sum += __shfl_xor(sum, 32);
  const float inv = 1.f / sum;

  // PV: e * v[jc] segment -> LDS transpose (v already in registers)
  {
    const float ee = ok ? e : 0.f;   // clamped lanes contribute 0
    f32x4 w0, w1, w2, w3;
#pragma unroll
    for (int g = 0; g < 4; ++g) {
      w0[g] = ee * (bf2f((ushort)va0[g])     + bf2f((ushort)vb0[g]));
      w1[g] = ee * (bf2f((ushort)va0[4 + g]) + bf2f((ushort)vb0[4 + g]));
      w2[g] = ee * (bf2f((ushort)va1[g])     + bf2f((ushort)vb1[g]));
      w3[g] = ee * (bf2f((ushort)va1[4 + g]) + bf2f((ushort)vb1[4 + g]));
    }
    *(f32x4*)&plds[wv][jj][ds * 16]      = w0;
    *(f32x4*)&plds[wv][jj][ds * 16 + 4]  = w1;
    *(f32x4*)&plds[wv][jj][ds * 16 + 8]  = w2;
    *(f32x4*)&plds[wv][jj][ds * 16 + 12] = w3;
  }
  asm volatile("s_waitcnt lgkmcnt(0)" ::: "memory");
  __builtin_amdgcn_sched_barrier(0);

  float o = 0.f;
#pragma unroll
  for (int q = 0; q < 16; ++q) o += plds[wv][q][lane];
  ao[(size_t)row * DIMC + h * HD + lane] = f2bf(o * inv);
}

// ---- proj split-K reduce: out = sum_z parts[z] + bias (fp32) ---------------
#define NR8 (M_ROWS * DIMC / 8)   // 201728
__global__ __launch_bounds__(256)
void reduce4_bias(const ushort* __restrict__ parts, const float* __restrict__ bias,
                  float* __restrict__ out) {
  int i = blockIdx.x * 256 + threadIdx.x;
  if (i >= NR8) return;
  const size_t slice = (size_t)M_ROWS * DIMC;
  float a[8];
#pragma unroll
  for (int e = 0; e < 8; ++e) a[e] = 0.f;
#pragma unroll
  for (int z = 0; z < 4; ++z) {
    s16x8 v = *(const s16x8*)(parts + z * slice + (size_t)i * 8);
#pragma unroll
    for (int e = 0; e < 8; ++e) a[e] += bf2f((ushort)v[e]);
  }
  const int col = (i * 8) & (DIMC - 1);
  f32x4 b0 = *(const f32x4*)(bias + col);
  f32x4 b1 = *(const f32x4*)(bias + col + 4);
  f32x4 o0 = {a[0] + b0.x, a[1] + b0.y, a[2] + b0.z, a[3] + b0.w};
  f32x4 o1 = {a[4] + b1.x, a[5] + b1.y, a[6] + b1.z, a[7] + b1.w};
  ((f32x4*)out)[2 * i]     = o0;
  ((f32x4*)out)[2 * i + 1] = o1;
}

// ----------------------------------------------------------------------------
extern "C" void kernel_launch(void* const* d_in, const int* in_sizes, int n_in,
                              void* d_out, int out_size, void* d_ws, size_t ws_size,
                              hipStream_t stream) {
  const float* x      = (const float*)d_in[0];
  const float* qkv_w  = (const float*)d_in[1];
  const float* proj_w = (const float*)d_in[2];
  const float* proj_b = (const float*)d_in[3];
  float* out = (float*)d_out;

  char* p = (char*)d_ws;
  ushort* x_bf    = (ushort*)p;  p += (size_t)M_PAD * DIMC * 2;
  ushort* qkvw_bf = (ushort*)p;  p += (size_t)3 * DIMC * DIMC * 2;
  ushort* projw_bf= (ushort*)p;  p += (size_t)DIMC * DIMC * 2;
  ushort* qkv_p   = (ushort*)p;  p += (size_t)2 * M_ROWS * 3 * DIMC * 2;
  ushort* ao_bf   = (ushort*)p;  p += (size_t)M_PAD * DIMC * 2;
  ushort* proj_p  = (ushort*)p;

  dim3 blk(256);

  {
    int total = NX + NQ + NP;
    cvt_all<<<dim3((total + 255) / 256), blk, 0, stream>>>(
        x, qkv_w, proj_w, x_bf, qkvw_bf, projw_bf);
  }

  // QKV GEMM: split-K=2, grid (7,48,2) = 672 blocks, bf16 partial slices
  gemm_bt_bf16<<<dim3(M_PAD / 128, (3 * DIMC) / 128, 2), blk, 0, stream>>>(
      x_bf, qkvw_bf, qkv_p, M_ROWS, 3 * DIMC, DIMC, DIMC / 2);

  // Local attention (+ qkv partial reduce) -> ao bf16
  int total_waves = B_SZ * HEADS * N_SEQ;  // 25216
  local_attn<<<dim3((total_waves + 3) / 4), blk, 0, stream>>>(
      qkv_p, qkv_p + (size_t)M_ROWS * 3 * DIMC, ao_bf);

  // Proj GEMM: split-K=4, grid (7,16,4) = 448 blocks, bf16 partial slices
  gemm_bt_bf16<<<dim3(M_PAD / 128, DIMC / 128, 4), blk, 0, stream>>>(
      ao_bf, projw_bf, proj_p, M_ROWS, DIMC, DIMC, DIMC / 4);

  // Reduce 4 proj partials + bias -> fp32 d_out
  reduce4_bias<<<dim3((NR8 + 255) / 256), blk, 0, stream>>>(proj_p, proj_b, out);
}